// Round 2
// baseline (725.446 us; speedup 1.0000x reference)
//
#include <hip/hip_runtime.h>
#include <math.h>

#define NTOK 32768
#define HDIM 1024
#define NEXP 64
#define NE   (NTOK * NEXP)
#define CAP  512
#define TB   32      // tokens per block
#define CK   64      // K-chunk
#define XRS  68      // LDS row stride (floats): 68%32=4 -> conflict-free b128
#define TIECAP 2048

__device__ __forceinline__ unsigned f2key(float f) {
  unsigned u = __float_as_uint(f);
  return (u & 0x80000000u) ? ~u : (u | 0x80000000u);
}

__global__ void init_kernel(unsigned* cnt, float* sumP) {
  int i = threadIdx.x;
  if (i < NEXP) { cnt[i] = 0u; sumP[i] = 0.f; }
}

// Block: 32 tokens x 64 experts, 4 waves. Wave (tokv,expv) covers a
// 16-token x 32-expert subtile; lane (tg,eg) computes 2 tok x 4 exp.
// All ds_read_b128 in the K-loop have 8 unique addrs x 8-way broadcast.
__global__ __launch_bounds__(256, 4) void router_kernel(
    const float* __restrict__ x, const float* __restrict__ w,
    float* __restrict__ probs, unsigned* __restrict__ keyNE,
    unsigned* __restrict__ keyEN, unsigned long long* __restrict__ assignB,
    unsigned* __restrict__ cnt, float* __restrict__ sumP,
    float* __restrict__ out) {
  __shared__ float sm[TB * XRS + NEXP * XRS];   // 26112 B
  float* xs  = sm;
  float* wsm = sm + TB * XRS;
  const int tid  = threadIdx.x;
  const int wid  = tid >> 6, lane = tid & 63;
  const int tokv = wid >> 1, expv = wid & 1;
  const int tg   = lane >> 3, eg = lane & 7;
  const int t0   = blockIdx.x * TB;

  float acc[2][4] = {};

  for (int hc = 0; hc < HDIM / CK; ++hc) {
    const int h0 = hc * CK;
#pragma unroll
    for (int r = 0; r < 2; ++r) {               // x: 32x64 = 512 float4
      int idx = tid + r * 256;
      int row = idx >> 4, c4 = idx & 15;
      *(float4*)(xs + row * XRS + c4 * 4) =
          *(const float4*)(x + (size_t)(t0 + row) * HDIM + h0 + c4 * 4);
    }
#pragma unroll
    for (int r = 0; r < 4; ++r) {               // w: 64x64 = 1024 float4
      int idx = tid + r * 256;
      int row = idx >> 4, c4 = idx & 15;
      *(float4*)(wsm + row * XRS + c4 * 4) =
          *(const float4*)(w + (size_t)row * HDIM + h0 + c4 * 4);
    }
    __syncthreads();
#pragma unroll
    for (int s = 0; s < CK / 4; ++s) {
      const int k4 = s * 4;
      float4 xv[2];
#pragma unroll
      for (int i = 0; i < 2; ++i)
        xv[i] = *(const float4*)(xs + (tokv * 16 + tg * 2 + i) * XRS + k4);
#pragma unroll
      for (int j = 0; j < 4; ++j) {
        float4 wv = *(const float4*)(wsm + (expv * 32 + j * 8 + eg) * XRS + k4);
#pragma unroll
        for (int i = 0; i < 2; ++i)
          acc[i][j] += xv[i].x * wv.x + xv[i].y * wv.y +
                       xv[i].z * wv.z + xv[i].w * wv.w;
      }
    }
    __syncthreads();
  }

  // Gather logits: ls[32][65]; keys: kt[32][65] (disjoint regions)
  float* ls = sm;
  unsigned* kt = (unsigned*)(sm + TB * 65 + 32);
#pragma unroll
  for (int i = 0; i < 2; ++i) {
    int tl = tokv * 16 + tg * 2 + i;
#pragma unroll
    for (int j = 0; j < 4; ++j)
      ls[tl * 65 + expv * 32 + j * 8 + eg] = acc[i][j];
  }
  __syncthreads();

  for (int i = 0; i < 8; ++i) {                 // wave handles 8 tokens
    const int tl = wid * 8 + i;
    const int t  = t0 + tl;
    float l = ls[tl * 65 + lane];
    float mx = l;
#pragma unroll
    for (int m = 32; m >= 1; m >>= 1) mx = fmaxf(mx, __shfl_xor(mx, m));
    float ex = expf(l - mx);
    float ssum = ex;
#pragma unroll
    for (int m = 32; m >= 1; m >>= 1) ssum += __shfl_xor(ssum, m);
    float p = ex / ssum;
    int rank = 0; float csum = p;
#pragma unroll
    for (int d = 1; d < 64; ++d) {
      float pj = __shfl_xor(p, d);
      int H = d; H |= H >> 1; H |= H >> 2; H |= H >> 4; H -= (H >> 1);
      bool jlt = (lane & H) != 0;               // j = lane^d < lane
      bool gt = (pj > p) || (pj == p && jlt);
      rank += gt ? 1 : 0;
      csum += gt ? pj : 0.f;
    }
    int kc = (csum >= 0.9f) ? rank : 63;
#pragma unroll
    for (int m = 32; m >= 1; m >>= 1) kc = min(kc, __shfl_xor(kc, m));
    const bool assign = (rank <= kc);
    float R = assign ? (p - (float)(rank + 1)) : -1e9f;
    unsigned key = f2key(R);
    probs[(size_t)t * NEXP + lane] = p;
    keyNE[(size_t)t * NEXP + lane] = key;
    kt[tl * 65 + lane] = key;
    unsigned long long ab = __ballot(assign);
    if (lane == 0) assignB[t] = ab;
    if (rank == 0) {
      out[(size_t)2 * NE + 1 + t] = (float)lane;
      atomicAdd(&cnt[lane], 1u);
      atomicAdd(&sumP[lane], p);
    }
  }
  __syncthreads();
#pragma unroll
  for (int r = 0; r < 8; ++r) {                 // [E][N] transposed keys
    int idx = tid + r * 256;
    int e = idx >> 5, tl = idx & 31;
    keyEN[(size_t)e * NTOK + t0 + tl] = kt[tl * 65 + e];
  }
}

// One block per expert: 4-pass MSB radix select for the C-th largest key,
// exact lowest-token-index tie resolution at the boundary.
__global__ __launch_bounds__(1024) void select_kernel(
    const unsigned* __restrict__ keyEN, unsigned* __restrict__ theta,
    int* __restrict__ tieCut, int* __restrict__ tieBuf) {
  const int e = blockIdx.x;
  const unsigned* col = keyEN + (size_t)e * NTOK;
  const int tid = threadIdx.x;
  __shared__ unsigned hist[256];
  __shared__ unsigned s_prefix, s_need, s_m, s_tn;
  __shared__ int s_cut;
  if (tid == 0) { s_prefix = 0u; s_need = CAP; }
  __syncthreads();
  for (int pass = 0; pass < 4; ++pass) {
    const int shift = 24 - 8 * pass;
    if (tid < 256) hist[tid] = 0u;
    __syncthreads();
    const unsigned prefix = s_prefix;
    for (int t = tid; t < NTOK; t += 1024) {
      unsigned k = col[t];
      bool match = (pass == 0) || ((k >> (shift + 8)) == (prefix >> (shift + 8)));
      if (match) atomicAdd(&hist[(k >> shift) & 255u], 1u);
    }
    __syncthreads();
    if (tid == 0) {
      unsigned need = s_need, cum = 0u;
      for (int d = 255; d >= 0; --d) {
        unsigned c = hist[d];
        if (cum + c >= need) {
          s_prefix = prefix | ((unsigned)d << shift);
          s_need = need - cum;
          s_m = c;
          break;
        }
        cum += c;
      }
    }
    __syncthreads();
  }
  const unsigned th = s_prefix;
  const unsigned need = s_need;
  const unsigned m = s_m;
  const unsigned UNASS = f2key(-1e9f);
  int cut;
  if (th == UNASS) {
    cut = -1;
  } else if (m == need) {
    cut = 0x7fffffff;
  } else {
    if (tid == 0) s_tn = 0u;
    __syncthreads();
    int* buf = tieBuf + e * TIECAP;
    for (int t = tid; t < NTOK; t += 1024) {
      if (col[t] == th) {
        unsigned i = atomicAdd(&s_tn, 1u);
        if (i < TIECAP) buf[i] = t;
      }
    }
    __syncthreads();
    int mm = (int)min(s_tn, (unsigned)TIECAP);
    for (int i = tid; i < mm; i += 1024) {
      int ti = buf[i];
      int less = 0;
      for (int j = 0; j < mm; ++j) less += (buf[j] < ti) ? 1 : 0;
      if (less == (int)need - 1) s_cut = ti;
    }
    __syncthreads();
    cut = s_cut;
  }
  if (tid == 0) { theta[e] = th; tieCut[e] = cut; }
}

__global__ __launch_bounds__(256) void write_kernel(
    const float* __restrict__ probs, const unsigned* __restrict__ keyNE,
    const unsigned long long* __restrict__ assignB,
    const unsigned* __restrict__ theta, const int* __restrict__ tieCut,
    const unsigned* __restrict__ cnt, const float* __restrict__ sumP,
    float* __restrict__ out) {
  const int id = blockIdx.x * 256 + threadIdx.x;
  const int t = id >> 6, e = id & 63;
  unsigned k = keyNE[id];
  float p = probs[id];
  bool a = (assignB[t] >> e) & 1ull;
  unsigned th = theta[e];
  int cut = tieCut[e];
  bool keep = (k > th) || ((k == th) && (t <= cut));
  bool msk = a && keep;
  out[id] = msk ? 1.f : 0.f;
  out[(size_t)NE + id] = msk ? p : 0.f;
  if (blockIdx.x == 0 && threadIdx.x < 64) {    // fused aux loss
    int ee = threadIdx.x;
    float v = ((float)cnt[ee] / (float)NTOK) * (sumP[ee] / (float)NTOK);
#pragma unroll
    for (int m = 32; m >= 1; m >>= 1) v += __shfl_xor(v, m);
    if (ee == 0) out[(size_t)2 * NE] = (float)NEXP * v * 0.01f;
  }
}

extern "C" void kernel_launch(void* const* d_in, const int* in_sizes, int n_in,
                              void* d_out, int out_size, void* d_ws, size_t ws_size,
                              hipStream_t stream) {
  const float* x = (const float*)d_in[0];
  const float* w = (const float*)d_in[1];
  float* out = (float*)d_out;

  char* ws = (char*)d_ws;
  float* probs                 = (float*)ws;
  unsigned* keyNE              = (unsigned*)(probs + NE);
  unsigned* keyEN              = keyNE + NE;
  unsigned long long* assignB  = (unsigned long long*)(keyEN + NE);
  unsigned* cnt                = (unsigned*)(assignB + NTOK);
  float* sumP                  = (float*)(cnt + NEXP);
  unsigned* theta              = (unsigned*)(sumP + NEXP);
  int* tieCut                  = (int*)(theta + NEXP);
  int* tieBuf                  = tieCut + NEXP;

  init_kernel<<<1, 64, 0, stream>>>(cnt, sumP);
  router_kernel<<<NTOK / TB, 256, 0, stream>>>(x, w, probs, keyNE, keyEN,
                                               assignB, cnt, sumP, out);
  select_kernel<<<NEXP, 1024, 0, stream>>>(keyEN, theta, tieCut, tieBuf);
  write_kernel<<<NE / 256, 256, 0, stream>>>(probs, keyNE, assignB, theta,
                                             tieCut, cnt, sumP, out);
}

// Round 3
// 692.730 us; speedup vs baseline: 1.0472x; 1.0472x over previous
//
#include <hip/hip_runtime.h>
#include <math.h>

#define NTOK 32768
#define HDIM 1024
#define NEXP 64
#define NE   (NTOK * NEXP)
#define CAP  512
#define TB   64
#define CK   64
#define XRS  68      // LDS row stride: bank offset 4 per row -> conflict-free
#define CAND 6144
#define QMAX 2048

__device__ __forceinline__ unsigned f2key(float f) {
  unsigned u = __float_as_uint(f);
  return (u & 0x80000000u) ? ~u : (u | 0x80000000u);
}
// key -> rank. Assigned keys encode R = p-(rank+1) in (-64,0); -R in (rank,rank+1).
// Top bit set <=> R >= 0 (only possible when p==1.0 -> rank 0).
__device__ __forceinline__ int rank_of(unsigned k) {
  if (k & 0x80000000u) return 0;
  float f = __uint_as_float(~k);        // = -R > 0
  f = fminf(f, 64.5f);                  // unassigned (-1e9) -> 64
  return (int)f;
}

__global__ void init_kernel(unsigned* cnt, float* sumP) {
  int i = threadIdx.x;
  if (i < NEXP) { cnt[i] = 0u; sumP[i] = 0.f; }
}

// 512 threads, 8 waves. 64 tokens x 64 experts, full K. Wave (tokv 0..3, expv 0..1)
// covers 16 tok x 32 exp; lane (tg,eg) computes 2 tok x 4 exp. All inner
// ds_read_b128: 8 unique addrs x 8-way broadcast, conflict-free.
__global__ __launch_bounds__(512, 4) void router_kernel(
    const float* __restrict__ x, const float* __restrict__ w,
    float* __restrict__ probs, unsigned* __restrict__ keyNE,
    unsigned* __restrict__ keyEN, unsigned long long* __restrict__ assignB,
    unsigned* __restrict__ cnt, float* __restrict__ sumP,
    float* __restrict__ out) {
  __shared__ float sm[(TB + NEXP) * XRS];   // 34816 B
  float* xs  = sm;
  float* wsm = sm + TB * XRS;
  const int tid  = threadIdx.x;
  const int wid  = tid >> 6, lane = tid & 63;
  const int tokv = wid >> 1, expv = wid & 1;
  const int tg   = lane >> 3, eg = lane & 7;
  const int t0   = blockIdx.x * TB;

  float acc[2][4] = {};

  for (int hc = 0; hc < HDIM / CK; ++hc) {
    const int h0 = hc * CK;
#pragma unroll
    for (int r = 0; r < 2; ++r) {
      int idx = tid + r * 512;
      int row = idx >> 4, c4 = idx & 15;
      *(float4*)(xs + row * XRS + c4 * 4) =
          *(const float4*)(x + (size_t)(t0 + row) * HDIM + h0 + c4 * 4);
      *(float4*)(wsm + row * XRS + c4 * 4) =
          *(const float4*)(w + (size_t)row * HDIM + h0 + c4 * 4);
    }
    __syncthreads();
#pragma unroll
    for (int s = 0; s < 16; ++s) {
      const int k4 = s * 4;
      float4 xv0 = *(const float4*)(xs + (tokv * 16 + tg) * XRS + k4);
      float4 xv1 = *(const float4*)(xs + (tokv * 16 + 8 + tg) * XRS + k4);
#pragma unroll
      for (int j = 0; j < 4; ++j) {
        float4 wv = *(const float4*)(wsm + (expv * 32 + j * 8 + eg) * XRS + k4);
        acc[0][j] += xv0.x * wv.x + xv0.y * wv.y + xv0.z * wv.z + xv0.w * wv.w;
        acc[1][j] += xv1.x * wv.x + xv1.y * wv.y + xv1.z * wv.z + xv1.w * wv.w;
      }
    }
    __syncthreads();
  }

  // Epilogue: logits through LDS, then per-token wave math (verified in R2).
  float* ls = sm;                                 // [64][65] floats
  unsigned* kt = (unsigned*)(sm + TB * 65);       // [64][65] keys
#pragma unroll
  for (int i = 0; i < 2; ++i) {
    int tl = tokv * 16 + i * 8 + tg;
#pragma unroll
    for (int j = 0; j < 4; ++j)
      ls[tl * 65 + expv * 32 + j * 8 + eg] = acc[i][j];
  }
  __syncthreads();

  for (int i = 0; i < 8; ++i) {
    const int tl = wid * 8 + i;
    const int t  = t0 + tl;
    float l = ls[tl * 65 + lane];
    float mx = l;
#pragma unroll
    for (int m = 32; m >= 1; m >>= 1) mx = fmaxf(mx, __shfl_xor(mx, m));
    float ex = expf(l - mx);
    float ssum = ex;
#pragma unroll
    for (int m = 32; m >= 1; m >>= 1) ssum += __shfl_xor(ssum, m);
    float p = ex / ssum;
    int rank = 0; float csum = p;
#pragma unroll
    for (int d = 1; d < 64; ++d) {
      float pj = __shfl_xor(p, d);
      int H = d; H |= H >> 1; H |= H >> 2; H |= H >> 4; H -= (H >> 1);
      bool jlt = (lane & H) != 0;                 // j = lane^d < lane
      bool gt = (pj > p) || (pj == p && jlt);
      rank += gt ? 1 : 0;
      csum += gt ? pj : 0.f;
    }
    int kc = (csum >= 0.9f) ? rank : 63;
#pragma unroll
    for (int m = 32; m >= 1; m >>= 1) kc = min(kc, __shfl_xor(kc, m));
    const bool assign = (rank <= kc);
    float R = assign ? (p - (float)(rank + 1)) : -1e9f;
    unsigned key = f2key(R);
    probs[(size_t)t * NEXP + lane] = p;
    keyNE[(size_t)t * NEXP + lane] = key;
    kt[tl * 65 + lane] = key;
    unsigned long long ab = __ballot(assign);
    if (lane == 0) assignB[t] = ab;
    if (rank == 0) {
      out[(size_t)2 * NE + 1 + t] = (float)lane;
      atomicAdd(&cnt[lane], 1u);
      atomicAdd(&sumP[lane], p);
    }
  }
  __syncthreads();
#pragma unroll
  for (int r = 0; r < 8; ++r) {
    int idx = tid + r * 512;
    int e = idx >> 6, tl = idx & 63;
    keyEN[(size_t)e * NTOK + t0 + tl] = kt[tl * 65 + e];
  }
}

// One block per expert. Rank-histogram (65 bins) -> boundary rank rb + need;
// extract rank==rb candidates to LDS; byte-narrow if large; exact quadratic
// (key desc, token asc) tie-cut.
__global__ __launch_bounds__(1024) void select_kernel(
    const unsigned* __restrict__ keyEN, unsigned* __restrict__ theta,
    int* __restrict__ tieCut) {
  const int e = blockIdx.x;
  const unsigned* col = keyEN + (size_t)e * NTOK;
  const int tid = threadIdx.x, wid = tid >> 6;
  __shared__ unsigned wh[16][256];
  __shared__ unsigned h[256];
  __shared__ unsigned cA_k[CAND], cA_t[CAND], cB_k[CAND], cB_t[CAND];
  __shared__ unsigned s_n, s_b;
  __shared__ int s_rb, s_need, s_cnt;
  __shared__ unsigned s_theta; __shared__ int s_cut;

  // pass 0: rank histogram
  for (int r = tid; r < 16 * 256; r += 1024) ((unsigned*)wh)[r] = 0u;
  __syncthreads();
  for (int t = tid; t < NTOK; t += 1024)
    atomicAdd(&wh[wid][rank_of(col[t])], 1u);
  __syncthreads();
  if (tid < 256) {
    unsigned s = 0;
    for (int wv = 0; wv < 16; ++wv) s += wh[wv][tid];
    h[tid] = s;
  }
  __syncthreads();
  if (tid == 0) {
    unsigned run = 0; int rb = -1; int need = 0;
    for (int r = 0; r < 64; ++r) {
      if (rb < 0 && run + h[r] >= CAP) { rb = r; need = CAP - (int)run; }
      run += h[r];
    }
    s_rb = rb; s_need = need; s_cnt = (rb >= 0) ? (int)h[rb] : 0;
  }
  __syncthreads();
  if (s_rb < 0) {   // fewer than CAP assigned in total: keep all assigned
    if (tid == 0) { theta[e] = f2key(-1e9f); tieCut[e] = -1; }
    return;
  }
  const int rb = s_rb;
  int need = s_need, cnt = s_cnt;
  unsigned pmask = 0u, pval = 0u;
  int level = 0;

  // global byte-narrowing (rare; only if the boundary-rank population is huge)
  while (cnt > CAND && level < 4) {
    const int sh = 24 - 8 * level;
    for (int r = tid; r < 16 * 256; r += 1024) ((unsigned*)wh)[r] = 0u;
    __syncthreads();
    for (int t = tid; t < NTOK; t += 1024) {
      unsigned k = col[t];
      if (rank_of(k) == rb && (k & pmask) == pval)
        atomicAdd(&wh[wid][(k >> sh) & 255u], 1u);
    }
    __syncthreads();
    if (tid < 256) {
      unsigned s = 0;
      for (int wv = 0; wv < 16; ++wv) s += wh[wv][tid];
      h[tid] = s;
    }
    __syncthreads();
    if (tid == 0) {
      unsigned cum = 0;
      for (int d = 255; d >= 0; --d) {
        if (cum + h[d] >= (unsigned)need) {
          s_b = (unsigned)d; s_need = need - (int)cum; s_cnt = (int)h[d];
          break;
        }
        cum += h[d];
      }
    }
    __syncthreads();
    need = s_need; cnt = s_cnt;
    pmask |= (255u << sh); pval |= (s_b << sh);
    level++;
    __syncthreads();
  }

  if (cnt > CAND) {   // level==4: key fully determined == pval; tie on token idx
    int lo = 0, hi = NTOK - 1;
    while (lo < hi) {
      int mid = (lo + hi) >> 1;
      if (tid == 0) s_n = 0u;
      __syncthreads();
      for (int t = tid; t <= mid; t += 1024)
        if (col[t] == pval) atomicAdd(&s_n, 1u);
      __syncthreads();
      if ((int)s_n >= need) hi = mid; else lo = mid + 1;
      __syncthreads();
    }
    if (tid == 0) { theta[e] = pval; tieCut[e] = lo; }
    return;
  }

  // extract candidates
  if (tid == 0) s_n = 0u;
  __syncthreads();
  for (int t = tid; t < NTOK; t += 1024) {
    unsigned k = col[t];
    if (rank_of(k) == rb && (k & pmask) == pval) {
      unsigned i = atomicAdd(&s_n, 1u);
      cA_k[i] = k; cA_t[i] = (unsigned)t;
    }
  }
  __syncthreads();
  unsigned* ck = cA_k; unsigned* ct = cA_t;
  unsigned* nk = cB_k; unsigned* nt2 = cB_t;

  // in-LDS byte-narrowing
  while (cnt > QMAX && level < 4) {
    const int sh = 24 - 8 * level;
    for (int r = tid; r < 16 * 256; r += 1024) ((unsigned*)wh)[r] = 0u;
    __syncthreads();
    for (int i = tid; i < cnt; i += 1024)
      atomicAdd(&wh[wid][(ck[i] >> sh) & 255u], 1u);
    __syncthreads();
    if (tid < 256) {
      unsigned s = 0;
      for (int wv = 0; wv < 16; ++wv) s += wh[wv][tid];
      h[tid] = s;
    }
    __syncthreads();
    if (tid == 0) {
      unsigned cum = 0;
      for (int d = 255; d >= 0; --d) {
        if (cum + h[d] >= (unsigned)need) {
          s_b = (unsigned)d; s_need = need - (int)cum; s_cnt = (int)h[d];
          break;
        }
        cum += h[d];
      }
      s_n = 0u;
    }
    __syncthreads();
    for (int i = tid; i < cnt; i += 1024) {
      if (((ck[i] >> sh) & 255u) == s_b) {
        unsigned j = atomicAdd(&s_n, 1u);
        nk[j] = ck[i]; nt2[j] = ct[i];
      }
    }
    __syncthreads();
    { unsigned* t1 = ck; ck = nk; nk = t1; t1 = ct; ct = nt2; nt2 = t1; }
    need = s_need; cnt = s_cnt; level++;
    __syncthreads();
  }

  // exact selection: need-th in strict order (key desc, token asc)
  for (int i = tid; i < cnt; i += 1024) {
    unsigned ki = ck[i], ti = ct[i];
    int c = 0;
    for (int j = 0; j < cnt; ++j) {
      unsigned kj = ck[j], tj = ct[j];
      c += (kj > ki || (kj == ki && tj < ti)) ? 1 : 0;
    }
    if (c == need - 1) { s_theta = ki; s_cut = (int)ti; }
  }
  __syncthreads();
  if (tid == 0) { theta[e] = s_theta; tieCut[e] = s_cut; }
}

__global__ __launch_bounds__(256) void write_kernel(
    const float* __restrict__ probs, const unsigned* __restrict__ keyNE,
    const unsigned long long* __restrict__ assignB,
    const unsigned* __restrict__ theta, const int* __restrict__ tieCut,
    const unsigned* __restrict__ cnt, const float* __restrict__ sumP,
    float* __restrict__ out) {
  const int id = blockIdx.x * 256 + threadIdx.x;
  const int t = id >> 6, e = id & 63;
  unsigned k = keyNE[id];
  float p = probs[id];
  bool a = (assignB[t] >> e) & 1ull;
  unsigned th = theta[e];
  int cut = tieCut[e];
  bool keep = (k > th) || ((k == th) && (t <= cut));
  bool msk = a && keep;
  out[id] = msk ? 1.f : 0.f;
  out[(size_t)NE + id] = msk ? p : 0.f;
  if (blockIdx.x == 0 && threadIdx.x < 64) {
    int ee = threadIdx.x;
    float v = ((float)cnt[ee] / (float)NTOK) * (sumP[ee] / (float)NTOK);
#pragma unroll
    for (int m = 32; m >= 1; m >>= 1) v += __shfl_xor(v, m);
    if (ee == 0) out[(size_t)2 * NE] = (float)NEXP * v * 0.01f;
  }
}

extern "C" void kernel_launch(void* const* d_in, const int* in_sizes, int n_in,
                              void* d_out, int out_size, void* d_ws, size_t ws_size,
                              hipStream_t stream) {
  const float* x = (const float*)d_in[0];
  const float* w = (const float*)d_in[1];
  float* out = (float*)d_out;

  char* ws = (char*)d_ws;
  float* probs                 = (float*)ws;
  unsigned* keyNE              = (unsigned*)(probs + NE);
  unsigned* keyEN              = keyNE + NE;
  unsigned long long* assignB  = (unsigned long long*)(keyEN + NE);
  unsigned* cnt                = (unsigned*)(assignB + NTOK);
  float* sumP                  = (float*)(cnt + NEXP);
  unsigned* theta              = (unsigned*)(sumP + NEXP);
  int* tieCut                  = (int*)(theta + NEXP);

  init_kernel<<<1, 64, 0, stream>>>(cnt, sumP);
  router_kernel<<<NTOK / TB, 512, 0, stream>>>(x, w, probs, keyNE, keyEN,
                                               assignB, cnt, sumP, out);
  select_kernel<<<NEXP, 1024, 0, stream>>>(keyEN, theta, tieCut);
  write_kernel<<<NE / 256, 256, 0, stream>>>(probs, keyNE, assignB, theta,
                                             tieCut, cnt, sumP, out);
}

// Round 4
// 535.366 us; speedup vs baseline: 1.3550x; 1.2939x over previous
//
#include <hip/hip_runtime.h>
#include <math.h>

#define NTOK 32768
#define HDIM 1024
#define NEXP 64
#define NE   (NTOK * NEXP)
#define CAP  512
#define TB   64
#define CK   64
#define XRS  68      // LDS row stride: bank offset 4 per row -> conflict-free
#define CAND 6144
#define QMAX 2048

__device__ __forceinline__ unsigned f2key(float f) {
  unsigned u = __float_as_uint(f);
  return (u & 0x80000000u) ? ~u : (u | 0x80000000u);
}
// Pure key-range coarsening: bin r holds keys with -R in [r, r+1); bin 64 =
// unassigned sentinel. Used consistently in histogram AND extraction, so
// selection is exact regardless of float-rounding at bin edges.
__device__ __forceinline__ int bin_of(unsigned k) {
  if (k & 0x80000000u) return 0;
  float f = __uint_as_float(~k);        // = -R > 0
  f = fminf(f, 64.5f);
  return (int)f;
}

__global__ void init_kernel(unsigned* cnt, float* sumP, unsigned* ghist) {
  int i = blockIdx.x * 256 + threadIdx.x;
  if (i < NEXP) { cnt[i] = 0u; sumP[i] = 0.f; }
  if (i < NEXP * NEXP) ghist[i] = 0u;
}

// 512 threads, 8 waves, 64 tok x 64 exp per block. NO min-occupancy arg in
// launch_bounds: (512,4) in R2/R3 forced a 64-VGPR budget -> ~525 MB of
// scratch-spill traffic (WRITE_SIZE 27->549 MB). R1's unconstrained build
// (VGPR 124) had zero spill.
__global__ __launch_bounds__(512) void router_kernel(
    const float* __restrict__ x, const float* __restrict__ w,
    float* __restrict__ probs, unsigned* __restrict__ keyNE,
    unsigned* __restrict__ keyEN, unsigned long long* __restrict__ assignB,
    unsigned* __restrict__ cnt, float* __restrict__ sumP,
    unsigned* __restrict__ ghist, float* __restrict__ out) {
  __shared__ float sm[(TB + NEXP) * XRS];     // 34816 B (reused by epilogue)
  __shared__ unsigned lhist[NEXP * 65];       // 16640 B rank histogram
  const int tid  = threadIdx.x;
  const int wid  = tid >> 6, lane = tid & 63;
  const int tokv = wid >> 1, expv = wid & 1;
  const int tg   = lane >> 3, eg = lane & 7;
  const int t0   = blockIdx.x * TB;
  float* xs  = sm;
  float* wsm = sm + TB * XRS;

  for (int i = tid; i < NEXP * 65; i += 512) lhist[i] = 0u;

  float acc[2][4] = {};

  for (int hc = 0; hc < HDIM / CK; ++hc) {
    const int h0 = hc * CK;
#pragma unroll
    for (int r = 0; r < 2; ++r) {
      int idx = tid + r * 512;
      int row = idx >> 4, c4 = idx & 15;
      *(float4*)(xs + row * XRS + c4 * 4) =
          *(const float4*)(x + (size_t)(t0 + row) * HDIM + h0 + c4 * 4);
      *(float4*)(wsm + row * XRS + c4 * 4) =
          *(const float4*)(w + (size_t)row * HDIM + h0 + c4 * 4);
    }
    __syncthreads();
#pragma unroll
    for (int s = 0; s < 16; ++s) {
      const int k4 = s * 4;
      float4 xv0 = *(const float4*)(xs + (tokv * 16 + tg) * XRS + k4);
      float4 xv1 = *(const float4*)(xs + (tokv * 16 + 8 + tg) * XRS + k4);
#pragma unroll
      for (int j = 0; j < 4; ++j) {
        float4 wv = *(const float4*)(wsm + (expv * 32 + j * 8 + eg) * XRS + k4);
        acc[0][j] += xv0.x * wv.x + xv0.y * wv.y + xv0.z * wv.z + xv0.w * wv.w;
        acc[1][j] += xv1.x * wv.x + xv1.y * wv.y + xv1.z * wv.z + xv1.w * wv.w;
      }
    }
    __syncthreads();
  }

  float* ls = sm;                                 // [64][65] logits
  unsigned* kt = (unsigned*)(sm + TB * 65);       // [64][65] keys
#pragma unroll
  for (int i = 0; i < 2; ++i) {
    int tl = tokv * 16 + i * 8 + tg;
#pragma unroll
    for (int j = 0; j < 4; ++j)
      ls[tl * 65 + expv * 32 + j * 8 + eg] = acc[i][j];
  }
  __syncthreads();

  for (int i = 0; i < 8; ++i) {
    const int tl = wid * 8 + i;
    const int t  = t0 + tl;
    float l = ls[tl * 65 + lane];
    float mx = l;
#pragma unroll
    for (int m = 32; m >= 1; m >>= 1) mx = fmaxf(mx, __shfl_xor(mx, m));
    float ex = expf(l - mx);
    float ssum = ex;
#pragma unroll
    for (int m = 32; m >= 1; m >>= 1) ssum += __shfl_xor(ssum, m);
    float p = ex / ssum;
    int rank = 0; float csum = p;
#pragma unroll
    for (int d = 1; d < 64; ++d) {
      float pj = __shfl_xor(p, d);
      int H = d; H |= H >> 1; H |= H >> 2; H |= H >> 4; H -= (H >> 1);
      bool jlt = (lane & H) != 0;                 // j = lane^d < lane
      bool gt = (pj > p) || (pj == p && jlt);
      rank += gt ? 1 : 0;
      csum += gt ? pj : 0.f;
    }
    int kc = (csum >= 0.9f) ? rank : 63;
#pragma unroll
    for (int m = 32; m >= 1; m >>= 1) kc = min(kc, __shfl_xor(kc, m));
    const bool assign = (rank <= kc);
    float R = assign ? (p - (float)(rank + 1)) : -1e9f;
    unsigned key = f2key(R);
    probs[(size_t)t * NEXP + lane] = p;
    keyNE[(size_t)t * NEXP + lane] = key;
    kt[tl * 65 + lane] = key;
    // 64 lanes -> 64 distinct expert rows: zero same-address LDS conflicts
    atomicAdd(&lhist[lane * 65 + bin_of(key)], 1u);
    unsigned long long ab = __ballot(assign);
    if (lane == 0) assignB[t] = ab;
    if (rank == 0) {
      out[(size_t)2 * NE + 1 + t] = (float)lane;
      atomicAdd(&cnt[lane], 1u);
      atomicAdd(&sumP[lane], p);
    }
  }
  __syncthreads();
#pragma unroll
  for (int r = 0; r < 8; ++r) {
    int idx = tid + r * 512;
    int e = idx >> 6, tl = idx & 63;
    keyEN[(size_t)e * NTOK + t0 + tl] = kt[tl * 65 + e];
  }
  for (int idx = tid; idx < NEXP * NEXP; idx += 512) {   // merge nonzero bins
    int ee = idx >> 6, b = idx & 63;
    unsigned v = lhist[ee * 65 + b];
    if (v) atomicAdd(&ghist[idx], v);
  }
}

// One block per expert. Boundary bin comes precomputed from ghist; one
// extraction scan + exact (key desc, token asc) quadratic tie-cut, with
// byte-narrowing backstops for pathological bin populations.
__global__ __launch_bounds__(1024) void select_kernel(
    const unsigned* __restrict__ keyEN, const unsigned* __restrict__ ghist,
    unsigned* __restrict__ theta, int* __restrict__ tieCut) {
  const int e = blockIdx.x;
  const unsigned* col = keyEN + (size_t)e * NTOK;
  const int tid = threadIdx.x, wid = tid >> 6;
  __shared__ unsigned wh[16][256];
  __shared__ unsigned h[256];
  __shared__ unsigned cA_k[CAND], cA_t[CAND], cB_k[CAND], cB_t[CAND];
  __shared__ unsigned s_n, s_b;
  __shared__ int s_rb, s_need, s_cnt;
  __shared__ unsigned s_theta; __shared__ int s_cut;

  if (tid == 0) {
    unsigned run = 0; int rb = -1, need = 0, cc = 0;
    for (int r = 0; r < 64; ++r) {
      unsigned c = ghist[e * 64 + r];
      if (rb < 0 && run + c >= CAP) { rb = r; need = CAP - (int)run; cc = (int)c; }
      run += c;
    }
    s_rb = rb; s_need = need; s_cnt = cc;
  }
  __syncthreads();
  if (s_rb < 0) {   // fewer than CAP assigned: keep all assigned
    if (tid == 0) { theta[e] = f2key(-1e9f); tieCut[e] = -1; }
    return;
  }
  const int rb = s_rb;
  int need = s_need, cnt = s_cnt;
  unsigned pmask = 0u, pval = 0u;
  int level = 0;

  while (cnt > CAND && level < 4) {   // global byte-narrowing (backstop)
    const int sh = 24 - 8 * level;
    for (int r = tid; r < 16 * 256; r += 1024) ((unsigned*)wh)[r] = 0u;
    __syncthreads();
    for (int t = tid; t < NTOK; t += 1024) {
      unsigned k = col[t];
      if (bin_of(k) == rb && (k & pmask) == pval)
        atomicAdd(&wh[wid][(k >> sh) & 255u], 1u);
    }
    __syncthreads();
    if (tid < 256) {
      unsigned s = 0;
      for (int wv = 0; wv < 16; ++wv) s += wh[wv][tid];
      h[tid] = s;
    }
    __syncthreads();
    if (tid == 0) {
      unsigned cum = 0;
      for (int d = 255; d >= 0; --d) {
        if (cum + h[d] >= (unsigned)need) {
          s_b = (unsigned)d; s_need = need - (int)cum; s_cnt = (int)h[d];
          break;
        }
        cum += h[d];
      }
    }
    __syncthreads();
    need = s_need; cnt = s_cnt;
    pmask |= (255u << sh); pval |= (s_b << sh);
    level++;
    __syncthreads();
  }

  if (cnt > CAND) {   // key fully determined == pval; tie purely on token idx
    int lo = 0, hi = NTOK - 1;
    while (lo < hi) {
      int mid = (lo + hi) >> 1;
      if (tid == 0) s_n = 0u;
      __syncthreads();
      for (int t = tid; t <= mid; t += 1024)
        if (col[t] == pval) atomicAdd(&s_n, 1u);
      __syncthreads();
      if ((int)s_n >= need) hi = mid; else lo = mid + 1;
      __syncthreads();
    }
    if (tid == 0) { theta[e] = pval; tieCut[e] = lo; }
    return;
  }

  if (tid == 0) s_n = 0u;
  __syncthreads();
  for (int t = tid; t < NTOK; t += 1024) {   // extraction scan
    unsigned k = col[t];
    if (bin_of(k) == rb && (k & pmask) == pval) {
      unsigned i = atomicAdd(&s_n, 1u);
      cA_k[i] = k; cA_t[i] = (unsigned)t;
    }
  }
  __syncthreads();
  unsigned* ck = cA_k; unsigned* ct = cA_t;
  unsigned* nk = cB_k; unsigned* nt2 = cB_t;

  while (cnt > QMAX && level < 4) {   // in-LDS byte-narrowing
    const int sh = 24 - 8 * level;
    for (int r = tid; r < 16 * 256; r += 1024) ((unsigned*)wh)[r] = 0u;
    __syncthreads();
    for (int i = tid; i < cnt; i += 1024)
      atomicAdd(&wh[wid][(ck[i] >> sh) & 255u], 1u);
    __syncthreads();
    if (tid < 256) {
      unsigned s = 0;
      for (int wv = 0; wv < 16; ++wv) s += wh[wv][tid];
      h[tid] = s;
    }
    __syncthreads();
    if (tid == 0) {
      unsigned cum = 0;
      for (int d = 255; d >= 0; --d) {
        if (cum + h[d] >= (unsigned)need) {
          s_b = (unsigned)d; s_need = need - (int)cum; s_cnt = (int)h[d];
          break;
        }
        cum += h[d];
      }
      s_n = 0u;
    }
    __syncthreads();
    for (int i = tid; i < cnt; i += 1024) {
      if (((ck[i] >> sh) & 255u) == s_b) {
        unsigned j = atomicAdd(&s_n, 1u);
        nk[j] = ck[i]; nt2[j] = ct[i];
      }
    }
    __syncthreads();
    { unsigned* t1 = ck; ck = nk; nk = t1; t1 = ct; ct = nt2; nt2 = t1; }
    need = s_need; cnt = s_cnt; level++;
    __syncthreads();
  }

  for (int i = tid; i < cnt; i += 1024) {   // exact: need-th in strict order
    unsigned ki = ck[i], ti = ct[i];
    int c = 0;
    for (int j = 0; j < cnt; ++j) {
      unsigned kj = ck[j], tj = ct[j];
      c += (kj > ki || (kj == ki && tj < ti)) ? 1 : 0;
    }
    if (c == need - 1) { s_theta = ki; s_cut = (int)ti; }
  }
  __syncthreads();
  if (tid == 0) { theta[e] = s_theta; tieCut[e] = s_cut; }
}

__global__ __launch_bounds__(256) void write_kernel(
    const float* __restrict__ probs, const unsigned* __restrict__ keyNE,
    const unsigned long long* __restrict__ assignB,
    const unsigned* __restrict__ theta, const int* __restrict__ tieCut,
    const unsigned* __restrict__ cnt, const float* __restrict__ sumP,
    float* __restrict__ out) {
  const int id = blockIdx.x * 256 + threadIdx.x;
  const int t = id >> 6, e = id & 63;
  unsigned k = keyNE[id];
  float p = probs[id];
  bool a = (assignB[t] >> e) & 1ull;
  unsigned th = theta[e];
  int cut = tieCut[e];
  bool keep = (k > th) || ((k == th) && (t <= cut));
  bool msk = a && keep;
  out[id] = msk ? 1.f : 0.f;
  out[(size_t)NE + id] = msk ? p : 0.f;
  if (blockIdx.x == 0 && threadIdx.x < 64) {
    int ee = threadIdx.x;
    float v = ((float)cnt[ee] / (float)NTOK) * (sumP[ee] / (float)NTOK);
#pragma unroll
    for (int m = 32; m >= 1; m >>= 1) v += __shfl_xor(v, m);
    if (ee == 0) out[(size_t)2 * NE] = (float)NEXP * v * 0.01f;
  }
}

extern "C" void kernel_launch(void* const* d_in, const int* in_sizes, int n_in,
                              void* d_out, int out_size, void* d_ws, size_t ws_size,
                              hipStream_t stream) {
  const float* x = (const float*)d_in[0];
  const float* w = (const float*)d_in[1];
  float* out = (float*)d_out;

  char* ws = (char*)d_ws;
  float* probs                 = (float*)ws;
  unsigned* keyNE              = (unsigned*)(probs + NE);
  unsigned* keyEN              = keyNE + NE;
  unsigned long long* assignB  = (unsigned long long*)(keyEN + NE);
  unsigned* cnt                = (unsigned*)(assignB + NTOK);
  float* sumP                  = (float*)(cnt + NEXP);
  unsigned* theta              = (unsigned*)(sumP + NEXP);
  int* tieCut                  = (int*)(theta + NEXP);
  unsigned* ghist              = (unsigned*)(tieCut + NEXP);

  init_kernel<<<16, 256, 0, stream>>>(cnt, sumP, ghist);
  router_kernel<<<NTOK / TB, 512, 0, stream>>>(x, w, probs, keyNE, keyEN,
                                               assignB, cnt, sumP, ghist, out);
  select_kernel<<<NEXP, 1024, 0, stream>>>(keyEN, ghist, theta, tieCut);
  write_kernel<<<NE / 256, 256, 0, stream>>>(probs, keyNE, assignB, theta,
                                             tieCut, cnt, sumP, out);
}